// Round 11
// baseline (277.991 us; speedup 1.0000x reference)
//
#include <hip/hip_runtime.h>
#include <hip/hip_bf16.h>
#include <cstdint>
#include <cstddef>

// B=4, S=2048, D=768 causal attention, fp32 in/out, f16 MFMA compute.
// R10 = R8 resubmitted verbatim (2nd infra failure on this kernel; code
// audited for hang/OOB/graph-capture hazards - none found; prior infra
// failures R0/R6 passed verbatim on resubmit). Decision rule: one more
// attempt; a 3rd failure convicts the kernel -> fall back to R7 + bisect.
// R8: FUSED flash-style attention replaces g1+g2.
//   Evidence: three different operand-delivery structures for g1/g2 (LDS-free
//   ping-pong, dist-2, 512-thr, qkv-LDS port) ALL land at ~95-126 us combined
//   -> the two-pass materialized-E algorithm is the bottleneck (67 MB Et
//   round-trip + atomics + serialization), not scheduling. Eliminate it.
// fused_attn: grid 256 (1/CU, XCD-swizzled), 512 thr / 8 waves.
//   Block = one batch, two complementary 16-row Q stripes (s, 127-s):
//   KV-tile work = 17 units for EVERY block (perfect balance).
//   Per stripe: Q(16x768) staged fragment-tiled in LDS once; per KV tile
//   (128 keys): wave w computes S-slice 16x16 (K=768, Q from LDS, Kt frags
//   from global), exp+causal in-register, P relayed via 4KB fragment-tiled
//   LDS, PV accumulates per-wave 96-col O slice (Vtt frags from global).
//   Rowsum: per-lane partials -> shfl + tiny LDS reduce at end. No atomics.
// g0 (qkv) and cvt: frozen at R7-verified state (Q written ROW-MAJOR,
//   pre-scaled; K fragment-tiled; V^T fragment-tiled).
// Fragment-tiled layout: elem(r,c) at ((r>>4)*(C/8)+(c>>3))*128+(r&15)*8+(c&7)

typedef _Float16 f16x8 __attribute__((ext_vector_type(8)));
typedef float    f32x4 __attribute__((ext_vector_type(4)));

#define SOFTMAX_SCALE 0.036084391824351615f  // 1/sqrt(768)

// fragment-tiled element index; cd3 = C>>3 (chunks per 16-row group)
__device__ __forceinline__ int tix(int r, int c, int cd3) {
    return ((r >> 4) * cd3 + (c >> 3)) * 128 + ((r & 15) << 3) + (c & 7);
}

// ---------------- g0: QKV projection (R7-verified, frozen) --------------
__global__ __launch_bounds__(256, 2) void gemm_qkv(
    const _Float16* __restrict__ A, const _Float16* __restrict__ Bt,
    _Float16* __restrict__ OQ, _Float16* __restrict__ OK, _Float16* __restrict__ OV)
{
    const int flat = blockIdx.y * 18 + blockIdx.x;     // 0..1151, x-fast
    const int swz  = (flat & 7) * 144 + (flat >> 3);   // bijective (1152%8==0)
    const int tm = swz / 18, tn = swz % 18;
    const int m0 = tm * 128, n0 = tn * 128;
    const int tid  = threadIdx.x;
    const int lane = tid & 63, wave = tid >> 6;
    const int wm = (wave >> 1) * 64, wn = (wave & 1) * 64;
    const int qr = lane >> 4, ql = lane & 15;

    __shared__ _Float16 sA[128 * 64];

    const _Float16* Ab = A + (long long)m0 * 768;

    const _Float16* pB[4];
#pragma unroll
    for (int ni = 0; ni < 4; ++ni) {
        const int r0 = n0 + wn + ni * 16;
        pB[ni] = Bt + ((r0 >> 4) * 96 + qr) * 128 + ql * 8;
    }

    const int kIters = 768 / 64;

    f32x4 acc[4][4];
#pragma unroll
    for (int i = 0; i < 4; ++i)
#pragma unroll
        for (int j = 0; j < 4; ++j) acc[i][j] = (f32x4){0.f, 0.f, 0.f, 0.f};

    int sra[4], sgc[4];
#pragma unroll
    for (int t = 0; t < 4; ++t) {
        const int c = t * 256 + tid, r = c >> 3;
        sra[t] = r; sgc[t] = (c & 7) ^ (r & 7);
    }

    f16x8 pa[4];
    auto loadA = [&](int kt) {
        const int kk = kt * 64;
#pragma unroll
        for (int t = 0; t < 4; ++t)
            pa[t] = *(const f16x8*)(Ab + sra[t] * 768 + kk + sgc[t] * 8);
    };

    loadA(0);
    for (int kt = 0; kt < kIters; ++kt) {
#pragma unroll
        for (int t = 0; t < 4; ++t) ((f16x8*)sA)[t * 256 + tid] = pa[t];
        __syncthreads();

        f16x8 bF[2][4];
#pragma unroll
        for (int ks = 0; ks < 2; ++ks)
#pragma unroll
            for (int ni = 0; ni < 4; ++ni)
                bF[ks][ni] = *(const f16x8*)(pB[ni] + kt * 1024 + ks * 512);

        if (kt + 1 < kIters) loadA(kt + 1);

#pragma unroll
        for (int ks = 0; ks < 2; ++ks) {
            f16x8 aF[4];
#pragma unroll
            for (int mi = 0; mi < 4; ++mi) {
                const int r = wm + mi * 16 + ql;
                const int sc = (ks * 4 + qr) ^ (r & 7);
                aF[mi] = *(const f16x8*)&sA[r * 64 + sc * 8];
            }
#pragma unroll
            for (int mi = 0; mi < 4; ++mi)
#pragma unroll
                for (int ni = 0; ni < 4; ++ni)
                    acc[mi][ni] = __builtin_amdgcn_mfma_f32_16x16x32_f16(
                        aF[mi], bF[ks][ni], acc[mi][ni], 0, 0, 0);
        }
        __syncthreads();
    }

#pragma unroll
    for (int mi = 0; mi < 4; ++mi) {
#pragma unroll
        for (int ni = 0; ni < 4; ++ni) {
            const f32x4 v = acc[mi][ni];
            const int mbase = m0 + wm + mi * 16 + qr * 4;
            const int n     = n0 + wn + ni * 16 + ql;
#pragma unroll
            for (int r = 0; r < 4; ++r) {
                const int m = mbase + r;
                const float val = v[r];
                if (n < 768) {
                    // Q: ROW-MAJOR, pre-scaled (A-side of fused LDS path)
                    OQ[(long long)m * 768 + n] = (_Float16)(val * SOFTMAX_SCALE);
                } else if (n < 1536) {
                    OK[tix(m, n - 768, 96)] = (_Float16)val;
                } else {
                    const int b = m >> 11, s = m & 2047;
                    OV[tix(b * 768 + (n - 1536), s, 256)] = (_Float16)val;
                }
            }
        }
    }
}

// ---------------- fused: O = softmax(QK^T, causal) V --------------------
__global__ __launch_bounds__(512, 2) void fused_attn(
    const _Float16* __restrict__ Qr, const _Float16* __restrict__ Kt,
    const _Float16* __restrict__ Vtt, float* __restrict__ out)
{
    __shared__ _Float16 sQ[16 * 768];   // fragment-tiled: idx8 = c8*16 + r
    __shared__ _Float16 sP[16 * 128];   // fragment-tiled
    __shared__ float    sRS[8][16];

    const int bid = blockIdx.x;                 // 0..255
    const int swz = (bid & 7) * 32 + (bid >> 3);// bijective (256%8==0)
    const int bz  = swz >> 6;                   // batch 0..3
    const int pr  = swz & 63;                   // pair 0..63
    const int tid = threadIdx.x;
    const int lane = tid & 63, w = tid >> 6;    // wave 0..7
    const int qr = lane >> 4, ql = lane & 15;

    // Kt row chunk base for this wave (kv0=0): row = bz*2048 + 16w
    const _Float16* pK0 = Kt + (((bz * 2048 + 16 * w) >> 4) * 96 + qr) * 128 + ql * 8;
    // Vtt row chunk base: row = bz*768 + 96w (+16*ni later)
    const _Float16* pV0 = Vtt + (((bz * 768 + 96 * w) >> 4) * 256 + qr) * 128 + ql * 8;

    for (int half = 0; half < 2; ++half) {
        const int s  = half ? (127 - pr) : pr;  // stripe 0..127 (16 rows)
        const int m0 = s * 16;
        __syncthreads();   // guard sQ/sRS reuse across halves
        // stage Q (16x768) fragment-tiled into LDS; each thread 3 chunks
#pragma unroll
        for (int t = 0; t < 3; ++t) {
            const int j = t * 512 + tid;        // 0..1535
            const int r = j & 15, c8 = j >> 4;  // c8 0..95
            ((f16x8*)sQ)[c8 * 16 + r] =
                *(const f16x8*)(Qr + (long long)(bz * 2048 + m0 + r) * 768 + c8 * 8);
        }
        __syncthreads();

        const int nt = (s >> 3) + 1;            // causal KV tiles of 128

        f32x4 oacc[6];
#pragma unroll
        for (int i = 0; i < 6; ++i) oacc[i] = (f32x4){0.f, 0.f, 0.f, 0.f};
        float prs0 = 0.f, prs1 = 0.f, prs2 = 0.f, prs3 = 0.f;

        for (int kt = 0; kt < nt; ++kt) {
            // ---- S-slice: S[0:16][16w..16w+15] over K=768 ----
            const long long kOff = (long long)kt * 98304;  // 128 rows * 768
            f32x4 sacc = (f32x4){0.f, 0.f, 0.f, 0.f};
#pragma unroll
            for (int ks = 0; ks < 24; ++ks) {
                const f16x8 qf = *(const f16x8*)&sQ[(ks * 4 + qr) * 128 + ql * 8];
                const f16x8 kf = *(const f16x8*)(pK0 + kOff + ks * 512);
                sacc = __builtin_amdgcn_mfma_f32_16x16x32_f16(qf, kf, sacc, 0, 0, 0);
            }
            __syncthreads();   // all waves' PV of previous tile done
            // ---- exp + causal mask + P->LDS + rowsum partials ----
            const int n = kt * 128 + 16 * w + ql;
            const int mg = m0 + qr * 4;
            const int pi = ((16 * w + ql) >> 3) * 16;   // chunk base
            {
                const float e = (n <= mg + 0) ? __expf(sacc[0]) : 0.f;
                prs0 += e; sP[(pi + qr * 4 + 0) * 8 + (ql & 7)] = (_Float16)e;
            }
            {
                const float e = (n <= mg + 1) ? __expf(sacc[1]) : 0.f;
                prs1 += e; sP[(pi + qr * 4 + 1) * 8 + (ql & 7)] = (_Float16)e;
            }
            {
                const float e = (n <= mg + 2) ? __expf(sacc[2]) : 0.f;
                prs2 += e; sP[(pi + qr * 4 + 2) * 8 + (ql & 7)] = (_Float16)e;
            }
            {
                const float e = (n <= mg + 3) ? __expf(sacc[3]) : 0.f;
                prs3 += e; sP[(pi + qr * 4 + 3) * 8 + (ql & 7)] = (_Float16)e;
            }
            __syncthreads();   // P complete
            // ---- PV: oacc += P(16x128) * V(cols 96w..96w+95) ----
#pragma unroll
            for (int ks2 = 0; ks2 < 4; ++ks2) {
                const f16x8 pf = *(const f16x8*)&sP[((ks2 * 4 + qr) * 16 + ql) * 8];
#pragma unroll
                for (int ni = 0; ni < 6; ++ni) {
                    const f16x8 vf = *(const f16x8*)
                        (pV0 + ni * 32768 + kt * 2048 + ks2 * 512);
                    oacc[ni] = __builtin_amdgcn_mfma_f32_16x16x32_f16(
                        pf, vf, oacc[ni], 0, 0, 0);
                }
            }
        }

        // ---- rowsum: reduce over ql (16 lanes), then across 8 waves ----
        float r0 = prs0, r1 = prs1, r2 = prs2, r3 = prs3;
        r0 += __shfl_xor(r0, 1); r0 += __shfl_xor(r0, 2);
        r0 += __shfl_xor(r0, 4); r0 += __shfl_xor(r0, 8);
        r1 += __shfl_xor(r1, 1); r1 += __shfl_xor(r1, 2);
        r1 += __shfl_xor(r1, 4); r1 += __shfl_xor(r1, 8);
        r2 += __shfl_xor(r2, 1); r2 += __shfl_xor(r2, 2);
        r2 += __shfl_xor(r2, 4); r2 += __shfl_xor(r2, 8);
        r3 += __shfl_xor(r3, 1); r3 += __shfl_xor(r3, 2);
        r3 += __shfl_xor(r3, 4); r3 += __shfl_xor(r3, 8);
        if (ql == 0) {
            sRS[w][qr * 4 + 0] = r0; sRS[w][qr * 4 + 1] = r1;
            sRS[w][qr * 4 + 2] = r2; sRS[w][qr * 4 + 3] = r3;
        }
        __syncthreads();
        float rt[4];
#pragma unroll
        for (int rr = 0; rr < 4; ++rr) {
            float t2 = 0.f;
#pragma unroll
            for (int w2 = 0; w2 < 8; ++w2) t2 += sRS[w2][qr * 4 + rr];
            rt[rr] = 1.f / t2;
        }
        // ---- O write: rows m0+qr*4+rr, cols 96w+16ni+ql ----
#pragma unroll
        for (int ni = 0; ni < 6; ++ni) {
#pragma unroll
            for (int rr = 0; rr < 4; ++rr) {
                out[(long long)(bz * 2048 + m0 + qr * 4 + rr) * 768
                    + 96 * w + 16 * ni + ql] = oacc[ni][rr] * rt[rr];
            }
        }
    }
}

// ---------------- cvt: x -> f16 row-major, W -> f16 fragment-tiled ------
__global__ __launch_bounds__(256) void cvt_all(
    const float* __restrict__ x,  const float* __restrict__ wq,
    const float* __restrict__ wk, const float* __restrict__ wv,
    _Float16* __restrict__ xh, _Float16* __restrict__ Wht)
{
    const int ci = blockIdx.x * 256 + threadIdx.x;
    const int XC = 8192 * 768 / 8;               // 786432 x-chunks
    if (ci < XC) {
        const float4 v0 = ((const float4*)x)[ci * 2];
        const float4 v1 = ((const float4*)x)[ci * 2 + 1];
        f16x8 o = { (_Float16)v0.x, (_Float16)v0.y, (_Float16)v0.z, (_Float16)v0.w,
                    (_Float16)v1.x, (_Float16)v1.y, (_Float16)v1.z, (_Float16)v1.w };
        ((f16x8*)xh)[ci] = o;
    } else {
        // weights: one 16B tiled chunk per thread; writes coalesced.
        const int j = ci - XC;                   // < 2304*96 = 221184
        const int ql2 = j & 15, blk = j >> 4;
        const int c8 = blk % 96, grp = blk / 96;
        const int r = grp * 16 + ql2;            // 0..2303
        const int w = (r < 768) ? 0 : (r < 1536) ? 1 : 2;
        const float* src = (w == 0) ? wq : (w == 1) ? wk : wv;
        const int rr = r - w * 768;
        const float4 v0 = ((const float4*)src)[rr * 192 + c8 * 2];
        const float4 v1 = ((const float4*)src)[rr * 192 + c8 * 2 + 1];
        f16x8 o = { (_Float16)v0.x, (_Float16)v0.y, (_Float16)v0.z, (_Float16)v0.w,
                    (_Float16)v1.x, (_Float16)v1.y, (_Float16)v1.z, (_Float16)v1.w };
        ((f16x8*)Wht)[j] = o;
    }
}

extern "C" void kernel_launch(void* const* d_in, const int* in_sizes, int n_in,
                              void* d_out, int out_size, void* d_ws, size_t ws_size,
                              hipStream_t stream) {
    const float* x  = (const float*)d_in[0];
    const float* wq = (const float*)d_in[1];
    const float* wk = (const float*)d_in[2];
    const float* wv = (const float*)d_in[3];
    float* out = (float*)d_out;
    char* ws = (char*)d_ws;

    size_t off = 0;
    auto alloc = [&](size_t bytes) {
        void* p = ws + off;
        off = (off + bytes + 255) & ~(size_t)255;
        return p;
    };
    _Float16* xh  = (_Float16*)alloc(8192ll * 768 * 2);   // row-major
    _Float16* Wht = (_Float16*)alloc(2304ll * 768 * 2);   // frag-tiled
    _Float16* Qr  = (_Float16*)alloc(8192ll * 768 * 2);   // ROW-major, pre-scaled
    _Float16* Kt  = (_Float16*)alloc(8192ll * 768 * 2);   // frag-tiled
    _Float16* Vtt = (_Float16*)alloc(4ll * 768 * 2048 * 2);  // frag-tiled V^T

    const int XC = 8192 * 768 / 8, WC = 2304 * 96;
    cvt_all<<<(XC + WC) / 256, 256, 0, stream>>>(x, wq, wk, wv, xh, Wht);

    // Q/K/V projection: M=8192, N=2304, K=768 (128x128 tiles)
    gemm_qkv<<<dim3(18, 64, 1), 256, 0, stream>>>(xh, Wht, Qr, Kt, Vtt);

    // Fused causal attention: O = softmax(QK^T)V
    fused_attn<<<dim3(256, 1, 1), 512, 0, stream>>>(Qr, Kt, Vtt, out);
}

// Round 12
// 209.202 us; speedup vs baseline: 1.3288x; 1.3288x over previous
//
#include <hip/hip_runtime.h>
#include <hip/hip_bf16.h>
#include <cstdint>
#include <cstddef>

// B=4, S=2048, D=768 causal attention, fp32 in/out, f16 MFMA compute.
// R11: fused_attn v2 - latency-hiding restructure. v1 counters: MfmaUtil
// 6.7%, VALUBusy 4.3%, HBM 4.5%, occ 19% -> pure latency serialization:
// (1) 1 block/CU lockstep, (2) 24-deep dependent QK MFMA chain with
// unhoisted L2 K-loads (VGPR=56), (3) 2 barriers/tile, no overlap.
// Fixes: 512 blocks (one stripe each, pair-balanced per XCD, 2 blocks/CU,
// launch_bounds(512,4) caps VGPR 128); QK split into 2 chains + dist-1
// named-reg K prefetch; sP double-buffered -> ONE barrier/tile with
// QK(kt+1) || PV(kt) overlap (independent MFMA streams).
// g0 (qkv) and cvt: frozen at verified state.
// Fragment-tiled layout: elem(r,c) at ((r>>4)*(C/8)+(c>>3))*128+(r&15)*8+(c&7)

typedef _Float16 f16x8 __attribute__((ext_vector_type(8)));
typedef float    f32x4 __attribute__((ext_vector_type(4)));

#define SOFTMAX_SCALE 0.036084391824351615f  // 1/sqrt(768)

// fragment-tiled element index; cd3 = C>>3 (chunks per 16-row group)
__device__ __forceinline__ int tix(int r, int c, int cd3) {
    return ((r >> 4) * cd3 + (c >> 3)) * 128 + ((r & 15) << 3) + (c & 7);
}

// ---------------- g0: QKV projection (verified, frozen) -----------------
__global__ __launch_bounds__(256, 2) void gemm_qkv(
    const _Float16* __restrict__ A, const _Float16* __restrict__ Bt,
    _Float16* __restrict__ OQ, _Float16* __restrict__ OK, _Float16* __restrict__ OV)
{
    const int flat = blockIdx.y * 18 + blockIdx.x;     // 0..1151, x-fast
    const int swz  = (flat & 7) * 144 + (flat >> 3);   // bijective (1152%8==0)
    const int tm = swz / 18, tn = swz % 18;
    const int m0 = tm * 128, n0 = tn * 128;
    const int tid  = threadIdx.x;
    const int lane = tid & 63, wave = tid >> 6;
    const int wm = (wave >> 1) * 64, wn = (wave & 1) * 64;
    const int qr = lane >> 4, ql = lane & 15;

    __shared__ _Float16 sA[128 * 64];

    const _Float16* Ab = A + (long long)m0 * 768;

    const _Float16* pB[4];
#pragma unroll
    for (int ni = 0; ni < 4; ++ni) {
        const int r0 = n0 + wn + ni * 16;
        pB[ni] = Bt + ((r0 >> 4) * 96 + qr) * 128 + ql * 8;
    }

    const int kIters = 768 / 64;

    f32x4 acc[4][4];
#pragma unroll
    for (int i = 0; i < 4; ++i)
#pragma unroll
        for (int j = 0; j < 4; ++j) acc[i][j] = (f32x4){0.f, 0.f, 0.f, 0.f};

    int sra[4], sgc[4];
#pragma unroll
    for (int t = 0; t < 4; ++t) {
        const int c = t * 256 + tid, r = c >> 3;
        sra[t] = r; sgc[t] = (c & 7) ^ (r & 7);
    }

    f16x8 pa[4];
    auto loadA = [&](int kt) {
        const int kk = kt * 64;
#pragma unroll
        for (int t = 0; t < 4; ++t)
            pa[t] = *(const f16x8*)(Ab + sra[t] * 768 + kk + sgc[t] * 8);
    };

    loadA(0);
    for (int kt = 0; kt < kIters; ++kt) {
#pragma unroll
        for (int t = 0; t < 4; ++t) ((f16x8*)sA)[t * 256 + tid] = pa[t];
        __syncthreads();

        f16x8 bF[2][4];
#pragma unroll
        for (int ks = 0; ks < 2; ++ks)
#pragma unroll
            for (int ni = 0; ni < 4; ++ni)
                bF[ks][ni] = *(const f16x8*)(pB[ni] + kt * 1024 + ks * 512);

        if (kt + 1 < kIters) loadA(kt + 1);

#pragma unroll
        for (int ks = 0; ks < 2; ++ks) {
            f16x8 aF[4];
#pragma unroll
            for (int mi = 0; mi < 4; ++mi) {
                const int r = wm + mi * 16 + ql;
                const int sc = (ks * 4 + qr) ^ (r & 7);
                aF[mi] = *(const f16x8*)&sA[r * 64 + sc * 8];
            }
#pragma unroll
            for (int mi = 0; mi < 4; ++mi)
#pragma unroll
                for (int ni = 0; ni < 4; ++ni)
                    acc[mi][ni] = __builtin_amdgcn_mfma_f32_16x16x32_f16(
                        aF[mi], bF[ks][ni], acc[mi][ni], 0, 0, 0);
        }
        __syncthreads();
    }

#pragma unroll
    for (int mi = 0; mi < 4; ++mi) {
#pragma unroll
        for (int ni = 0; ni < 4; ++ni) {
            const f32x4 v = acc[mi][ni];
            const int mbase = m0 + wm + mi * 16 + qr * 4;
            const int n     = n0 + wn + ni * 16 + ql;
#pragma unroll
            for (int r = 0; r < 4; ++r) {
                const int m = mbase + r;
                const float val = v[r];
                if (n < 768) {
                    // Q: ROW-MAJOR, pre-scaled (A-side of fused LDS path)
                    OQ[(long long)m * 768 + n] = (_Float16)(val * SOFTMAX_SCALE);
                } else if (n < 1536) {
                    OK[tix(m, n - 768, 96)] = (_Float16)val;
                } else {
                    const int b = m >> 11, s = m & 2047;
                    OV[tix(b * 768 + (n - 1536), s, 256)] = (_Float16)val;
                }
            }
        }
    }
}

// ---------------- fused v2: O = softmax(QK^T, causal) V -----------------
__global__ __launch_bounds__(512, 4) void fused_attn(
    const _Float16* __restrict__ Qr, const _Float16* __restrict__ Kt,
    const _Float16* __restrict__ Vtt, float* __restrict__ out)
{
    __shared__ _Float16 sQ[16 * 768];    // fragment-tiled: idx8 = c8*16 + r
    __shared__ _Float16 sP[2][16 * 128]; // double-buffered P relay
    __shared__ float    sRS[8][16];

    // Block -> (batch, stripe): XCD x gets 32 complete complementary pairs
    // (544 tile-units each, balanced); pair members 32-apart in dispatch.
    const int b   = blockIdx.x;                 // 0..511
    const int x   = b & 7, j = b >> 3;          // XCD, 0..63
    const int m_  = (j >> 5) & 1;               // pair member
    const int pg  = x * 32 + (j & 31);          // pair 0..255
    const int bz  = pg >> 6;                    // batch 0..3
    const int pr  = pg & 63;                    // pair in batch
    const int s   = m_ ? pr : (127 - pr);       // stripe 0..127 (heavy first)
    const int m0  = s * 16;

    const int tid = threadIdx.x;
    const int lane = tid & 63, w = tid >> 6;    // wave 0..7
    const int qr = lane >> 4, ql = lane & 15;

    // Kt row chunk base for this wave (kv tile 0): row = bz*2048 + 16w
    const _Float16* pK0 = Kt + (((bz * 2048 + 16 * w) >> 4) * 96 + qr) * 128 + ql * 8;
    // Vtt row chunk base: row = bz*768 + 96w (+16*ni later)
    const _Float16* pV0 = Vtt + (((bz * 768 + 96 * w) >> 4) * 256 + qr) * 128 + ql * 8;

    // stage Q (16x768) fragment-tiled into LDS; each thread 3 chunks
#pragma unroll
    for (int t = 0; t < 3; ++t) {
        const int jj = t * 512 + tid;           // 0..1535
        const int r = jj & 15, c8 = jj >> 4;    // c8 0..95
        ((f16x8*)sQ)[c8 * 16 + r] =
            *(const f16x8*)(Qr + (long long)(bz * 2048 + m0 + r) * 768 + c8 * 8);
    }
    __syncthreads();

    const int nt = (s >> 3) + 1;                // causal KV tiles of 128

    f32x4 oacc[6];
#pragma unroll
    for (int i = 0; i < 6; ++i) oacc[i] = (f32x4){0.f, 0.f, 0.f, 0.f};
    float prs0 = 0.f, prs1 = 0.f, prs2 = 0.f, prs3 = 0.f;

    // ---- QK tile: 2 accumulator chains + dist-1 named-reg K prefetch ----
    auto qk_tile = [&](int kt2, f32x4& sv) {
        const _Float16* pKt = pK0 + (long long)kt2 * 98304;
        f32x4 s0 = (f32x4){0.f, 0.f, 0.f, 0.f};
        f32x4 s1 = (f32x4){0.f, 0.f, 0.f, 0.f};
        f16x8 k0 = *(const f16x8*)(pKt);
        f16x8 k1 = *(const f16x8*)(pKt + 512);
#pragma unroll
        for (int ks = 0; ks < 24; ks += 2) {
            const f16x8 q0 = *(const f16x8*)&sQ[(ks * 4 + qr) * 128 + ql * 8];
            const f16x8 q1 = *(const f16x8*)&sQ[((ks + 1) * 4 + qr) * 128 + ql * 8];
            f16x8 kn0, kn1;
            if (ks + 2 < 24) {
                kn0 = *(const f16x8*)(pKt + (ks + 2) * 512);
                kn1 = *(const f16x8*)(pKt + (ks + 3) * 512);
            }
            s0 = __builtin_amdgcn_mfma_f32_16x16x32_f16(q0, k0, s0, 0, 0, 0);
            s1 = __builtin_amdgcn_mfma_f32_16x16x32_f16(q1, k1, s1, 0, 0, 0);
            if (ks + 2 < 24) { k0 = kn0; k1 = kn1; }
        }
        sv = s0 + s1;
    };

    // ---- exp + causal mask + P->LDS buffer + rowsum partials ----
    auto expw = [&](int kt2, const f32x4& sv, _Float16* sPb) {
        const int n  = kt2 * 128 + 16 * w + ql;
        const int mg = m0 + qr * 4;
        const int pi = ((16 * w + ql) >> 3) * 16;
        {
            const float e = (n <= mg + 0) ? __expf(sv[0]) : 0.f;
            prs0 += e; sPb[(pi + qr * 4 + 0) * 8 + (ql & 7)] = (_Float16)e;
        }
        {
            const float e = (n <= mg + 1) ? __expf(sv[1]) : 0.f;
            prs1 += e; sPb[(pi + qr * 4 + 1) * 8 + (ql & 7)] = (_Float16)e;
        }
        {
            const float e = (n <= mg + 2) ? __expf(sv[2]) : 0.f;
            prs2 += e; sPb[(pi + qr * 4 + 2) * 8 + (ql & 7)] = (_Float16)e;
        }
        {
            const float e = (n <= mg + 3) ? __expf(sv[3]) : 0.f;
            prs3 += e; sPb[(pi + qr * 4 + 3) * 8 + (ql & 7)] = (_Float16)e;
        }
    };

    // ---- PV: oacc += P(16x128) * V(cols 96w..96w+95) ----
    auto pv = [&](int kt2, const _Float16* sPb) {
#pragma unroll
        for (int ks2 = 0; ks2 < 4; ++ks2) {
            const f16x8 pf = *(const f16x8*)&sPb[((ks2 * 4 + qr) * 16 + ql) * 8];
#pragma unroll
            for (int ni = 0; ni < 6; ++ni) {
                const f16x8 vf = *(const f16x8*)
                    (pV0 + ni * 32768 + (long long)kt2 * 2048 + ks2 * 512);
                oacc[ni] = __builtin_amdgcn_mfma_f32_16x16x32_f16(
                    pf, vf, oacc[ni], 0, 0, 0);
            }
        }
    };

    // prologue: tile 0 -> sP[0]
    {
        f32x4 sv;
        qk_tile(0, sv);
        expw(0, sv, sP[0]);
    }
    // steady state: ONE barrier per tile; QK(kt+1) || PV(kt) overlap
    for (int kt = 0; kt < nt; ++kt) {
        __syncthreads();           // sP[kt&1] complete; sP[(kt+1)&1] free
        if (kt + 1 < nt) {
            f32x4 sv;
            qk_tile(kt + 1, sv);   // independent of PV(kt) -> interleaves
            pv(kt, sP[kt & 1]);
            expw(kt + 1, sv, sP[(kt + 1) & 1]);
        } else {
            pv(kt, sP[kt & 1]);
        }
    }

    // ---- rowsum: reduce over ql (16 lanes), then across 8 waves ----
    float r0 = prs0, r1 = prs1, r2 = prs2, r3 = prs3;
    r0 += __shfl_xor(r0, 1); r0 += __shfl_xor(r0, 2);
    r0 += __shfl_xor(r0, 4); r0 += __shfl_xor(r0, 8);
    r1 += __shfl_xor(r1, 1); r1 += __shfl_xor(r1, 2);
    r1 += __shfl_xor(r1, 4); r1 += __shfl_xor(r1, 8);
    r2 += __shfl_xor(r2, 1); r2 += __shfl_xor(r2, 2);
    r2 += __shfl_xor(r2, 4); r2 += __shfl_xor(r2, 8);
    r3 += __shfl_xor(r3, 1); r3 += __shfl_xor(r3, 2);
    r3 += __shfl_xor(r3, 4); r3 += __shfl_xor(r3, 8);
    if (ql == 0) {
        sRS[w][qr * 4 + 0] = r0; sRS[w][qr * 4 + 1] = r1;
        sRS[w][qr * 4 + 2] = r2; sRS[w][qr * 4 + 3] = r3;
    }
    __syncthreads();
    float rt[4];
#pragma unroll
    for (int rr = 0; rr < 4; ++rr) {
        float t2 = 0.f;
#pragma unroll
        for (int w2 = 0; w2 < 8; ++w2) t2 += sRS[w2][qr * 4 + rr];
        rt[rr] = 1.f / t2;
    }
    // ---- O write: rows m0+qr*4+rr, cols 96w+16ni+ql ----
#pragma unroll
    for (int ni = 0; ni < 6; ++ni) {
#pragma unroll
        for (int rr = 0; rr < 4; ++rr) {
            out[(long long)(bz * 2048 + m0 + qr * 4 + rr) * 768
                + 96 * w + 16 * ni + ql] = oacc[ni][rr] * rt[rr];
        }
    }
}

// ---------------- cvt: x -> f16 row-major, W -> f16 fragment-tiled ------
__global__ __launch_bounds__(256) void cvt_all(
    const float* __restrict__ x,  const float* __restrict__ wq,
    const float* __restrict__ wk, const float* __restrict__ wv,
    _Float16* __restrict__ xh, _Float16* __restrict__ Wht)
{
    const int ci = blockIdx.x * 256 + threadIdx.x;
    const int XC = 8192 * 768 / 8;               // 786432 x-chunks
    if (ci < XC) {
        const float4 v0 = ((const float4*)x)[ci * 2];
        const float4 v1 = ((const float4*)x)[ci * 2 + 1];
        f16x8 o = { (_Float16)v0.x, (_Float16)v0.y, (_Float16)v0.z, (_Float16)v0.w,
                    (_Float16)v1.x, (_Float16)v1.y, (_Float16)v1.z, (_Float16)v1.w };
        ((f16x8*)xh)[ci] = o;
    } else {
        // weights: one 16B tiled chunk per thread; writes coalesced.
        const int j = ci - XC;                   // < 2304*96 = 221184
        const int ql2 = j & 15, blk = j >> 4;
        const int c8 = blk % 96, grp = blk / 96;
        const int r = grp * 16 + ql2;            // 0..2303
        const int w = (r < 768) ? 0 : (r < 1536) ? 1 : 2;
        const float* src = (w == 0) ? wq : (w == 1) ? wk : wv;
        const int rr = r - w * 768;
        const float4 v0 = ((const float4*)src)[rr * 192 + c8 * 2];
        const float4 v1 = ((const float4*)src)[rr * 192 + c8 * 2 + 1];
        f16x8 o = { (_Float16)v0.x, (_Float16)v0.y, (_Float16)v0.z, (_Float16)v0.w,
                    (_Float16)v1.x, (_Float16)v1.y, (_Float16)v1.z, (_Float16)v1.w };
        ((f16x8*)Wht)[j] = o;
    }
}

extern "C" void kernel_launch(void* const* d_in, const int* in_sizes, int n_in,
                              void* d_out, int out_size, void* d_ws, size_t ws_size,
                              hipStream_t stream) {
    const float* x  = (const float*)d_in[0];
    const float* wq = (const float*)d_in[1];
    const float* wk = (const float*)d_in[2];
    const float* wv = (const float*)d_in[3];
    float* out = (float*)d_out;
    char* ws = (char*)d_ws;

    size_t off = 0;
    auto alloc = [&](size_t bytes) {
        void* p = ws + off;
        off = (off + bytes + 255) & ~(size_t)255;
        return p;
    };
    _Float16* xh  = (_Float16*)alloc(8192ll * 768 * 2);   // row-major
    _Float16* Wht = (_Float16*)alloc(2304ll * 768 * 2);   // frag-tiled
    _Float16* Qr  = (_Float16*)alloc(8192ll * 768 * 2);   // ROW-major, pre-scaled
    _Float16* Kt  = (_Float16*)alloc(8192ll * 768 * 2);   // frag-tiled
    _Float16* Vtt = (_Float16*)alloc(4ll * 768 * 2048 * 2);  // frag-tiled V^T

    const int XC = 8192 * 768 / 8, WC = 2304 * 96;
    cvt_all<<<(XC + WC) / 256, 256, 0, stream>>>(x, wq, wk, wv, xh, Wht);

    // Q/K/V projection: M=8192, N=2304, K=768 (128x128 tiles)
    gemm_qkv<<<dim3(18, 64, 1), 256, 0, stream>>>(xh, Wht, Qr, Kt, Vtt);

    // Fused causal attention: O = softmax(QK^T)V, one stripe per block
    fused_attn<<<dim3(512, 1, 1), 512, 0, stream>>>(Qr, Kt, Vtt, out);
}

// Round 13
// 203.132 us; speedup vs baseline: 1.3685x; 1.0299x over previous
//
#include <hip/hip_runtime.h>
#include <hip/hip_bf16.h>
#include <cstdint>
#include <cstddef>

// B=4, S=2048, D=768 causal attention, fp32 in/out, f16 MFMA compute.
// R12 accounting: total - qkv - cvt - attn == ~60us residual across all
// rounds -> two-pass g1+g2 was ~65us, so fused must reach <65 to win.
// R13: deepen fused's ILP (v2: 88us, MfmaUtil 12.5%, VGPR only 64/128):
//  - QK: rolling dist-3 K-prefetch (ka[3]/kb[3], unroll-static indices)
//    covers ~200cy L2 latency (v2 dist-1 covered ~32cy -> ~170cy naked
//    stall x12 per tile).
//  - PV: ni-outer + ping-pong V-quad prefetch (va/vb[4], parity-static)
//    + P fragments hoisted once per tile (pfh[4], -20 LDS reads).
//  - Register budget ~124 of 128 cap; spill tripwire = WRITE_SIZE.
// g0 (qkv) and cvt: frozen at verified state.
// Fragment-tiled layout: elem(r,c) at ((r>>4)*(C/8)+(c>>3))*128+(r&15)*8+(c&7)

typedef _Float16 f16x8 __attribute__((ext_vector_type(8)));
typedef float    f32x4 __attribute__((ext_vector_type(4)));

#define SOFTMAX_SCALE 0.036084391824351615f  // 1/sqrt(768)

// fragment-tiled element index; cd3 = C>>3 (chunks per 16-row group)
__device__ __forceinline__ int tix(int r, int c, int cd3) {
    return ((r >> 4) * cd3 + (c >> 3)) * 128 + ((r & 15) << 3) + (c & 7);
}

// ---------------- g0: QKV projection (verified, frozen) -----------------
__global__ __launch_bounds__(256, 2) void gemm_qkv(
    const _Float16* __restrict__ A, const _Float16* __restrict__ Bt,
    _Float16* __restrict__ OQ, _Float16* __restrict__ OK, _Float16* __restrict__ OV)
{
    const int flat = blockIdx.y * 18 + blockIdx.x;     // 0..1151, x-fast
    const int swz  = (flat & 7) * 144 + (flat >> 3);   // bijective (1152%8==0)
    const int tm = swz / 18, tn = swz % 18;
    const int m0 = tm * 128, n0 = tn * 128;
    const int tid  = threadIdx.x;
    const int lane = tid & 63, wave = tid >> 6;
    const int wm = (wave >> 1) * 64, wn = (wave & 1) * 64;
    const int qr = lane >> 4, ql = lane & 15;

    __shared__ _Float16 sA[128 * 64];

    const _Float16* Ab = A + (long long)m0 * 768;

    const _Float16* pB[4];
#pragma unroll
    for (int ni = 0; ni < 4; ++ni) {
        const int r0 = n0 + wn + ni * 16;
        pB[ni] = Bt + ((r0 >> 4) * 96 + qr) * 128 + ql * 8;
    }

    const int kIters = 768 / 64;

    f32x4 acc[4][4];
#pragma unroll
    for (int i = 0; i < 4; ++i)
#pragma unroll
        for (int j = 0; j < 4; ++j) acc[i][j] = (f32x4){0.f, 0.f, 0.f, 0.f};

    int sra[4], sgc[4];
#pragma unroll
    for (int t = 0; t < 4; ++t) {
        const int c = t * 256 + tid, r = c >> 3;
        sra[t] = r; sgc[t] = (c & 7) ^ (r & 7);
    }

    f16x8 pa[4];
    auto loadA = [&](int kt) {
        const int kk = kt * 64;
#pragma unroll
        for (int t = 0; t < 4; ++t)
            pa[t] = *(const f16x8*)(Ab + sra[t] * 768 + kk + sgc[t] * 8);
    };

    loadA(0);
    for (int kt = 0; kt < kIters; ++kt) {
#pragma unroll
        for (int t = 0; t < 4; ++t) ((f16x8*)sA)[t * 256 + tid] = pa[t];
        __syncthreads();

        f16x8 bF[2][4];
#pragma unroll
        for (int ks = 0; ks < 2; ++ks)
#pragma unroll
            for (int ni = 0; ni < 4; ++ni)
                bF[ks][ni] = *(const f16x8*)(pB[ni] + kt * 1024 + ks * 512);

        if (kt + 1 < kIters) loadA(kt + 1);

#pragma unroll
        for (int ks = 0; ks < 2; ++ks) {
            f16x8 aF[4];
#pragma unroll
            for (int mi = 0; mi < 4; ++mi) {
                const int r = wm + mi * 16 + ql;
                const int sc = (ks * 4 + qr) ^ (r & 7);
                aF[mi] = *(const f16x8*)&sA[r * 64 + sc * 8];
            }
#pragma unroll
            for (int mi = 0; mi < 4; ++mi)
#pragma unroll
                for (int ni = 0; ni < 4; ++ni)
                    acc[mi][ni] = __builtin_amdgcn_mfma_f32_16x16x32_f16(
                        aF[mi], bF[ks][ni], acc[mi][ni], 0, 0, 0);
        }
        __syncthreads();
    }

#pragma unroll
    for (int mi = 0; mi < 4; ++mi) {
#pragma unroll
        for (int ni = 0; ni < 4; ++ni) {
            const f32x4 v = acc[mi][ni];
            const int mbase = m0 + wm + mi * 16 + qr * 4;
            const int n     = n0 + wn + ni * 16 + ql;
#pragma unroll
            for (int r = 0; r < 4; ++r) {
                const int m = mbase + r;
                const float val = v[r];
                if (n < 768) {
                    // Q: ROW-MAJOR, pre-scaled (A-side of fused LDS path)
                    OQ[(long long)m * 768 + n] = (_Float16)(val * SOFTMAX_SCALE);
                } else if (n < 1536) {
                    OK[tix(m, n - 768, 96)] = (_Float16)val;
                } else {
                    const int b = m >> 11, s = m & 2047;
                    OV[tix(b * 768 + (n - 1536), s, 256)] = (_Float16)val;
                }
            }
        }
    }
}

// ---------------- fused v3: O = softmax(QK^T, causal) V -----------------
__global__ __launch_bounds__(512, 4) void fused_attn(
    const _Float16* __restrict__ Qr, const _Float16* __restrict__ Kt,
    const _Float16* __restrict__ Vtt, float* __restrict__ out)
{
    __shared__ _Float16 sQ[16 * 768];    // fragment-tiled: idx8 = c8*16 + r
    __shared__ _Float16 sP[2][16 * 128]; // double-buffered P relay
    __shared__ float    sRS[8][16];

    // Block -> (batch, stripe): XCD x gets 32 complete complementary pairs
    // (544 tile-units each, balanced); pair members 32-apart in dispatch.
    const int b   = blockIdx.x;                 // 0..511
    const int x   = b & 7, j = b >> 3;          // XCD, 0..63
    const int m_  = (j >> 5) & 1;               // pair member
    const int pg  = x * 32 + (j & 31);          // pair 0..255
    const int bz  = pg >> 6;                    // batch 0..3
    const int pr  = pg & 63;                    // pair in batch
    const int s   = m_ ? pr : (127 - pr);       // stripe 0..127 (heavy first)
    const int m0  = s * 16;

    const int tid = threadIdx.x;
    const int lane = tid & 63, w = tid >> 6;    // wave 0..7
    const int qr = lane >> 4, ql = lane & 15;

    // Kt row chunk base for this wave (kv tile 0): row = bz*2048 + 16w
    const _Float16* pK0 = Kt + (((bz * 2048 + 16 * w) >> 4) * 96 + qr) * 128 + ql * 8;
    // Vtt row chunk base: row = bz*768 + 96w (+16*ni later)
    const _Float16* pV0 = Vtt + (((bz * 768 + 96 * w) >> 4) * 256 + qr) * 128 + ql * 8;

    // stage Q (16x768) fragment-tiled into LDS; each thread 3 chunks
#pragma unroll
    for (int t = 0; t < 3; ++t) {
        const int jj = t * 512 + tid;           // 0..1535
        const int r = jj & 15, c8 = jj >> 4;    // c8 0..95
        ((f16x8*)sQ)[c8 * 16 + r] =
            *(const f16x8*)(Qr + (long long)(bz * 2048 + m0 + r) * 768 + c8 * 8);
    }
    __syncthreads();

    const int nt = (s >> 3) + 1;                // causal KV tiles of 128

    f32x4 oacc[6];
#pragma unroll
    for (int i = 0; i < 6; ++i) oacc[i] = (f32x4){0.f, 0.f, 0.f, 0.f};
    float prs0 = 0.f, prs1 = 0.f, prs2 = 0.f, prs3 = 0.f;

    // ---- QK tile: 2 chains + rolling dist-3 K prefetch (static idx) ----
    auto qk_tile = [&](int kt2, f32x4& sv) {
        const _Float16* pKt = pK0 + (long long)kt2 * 98304;
        f32x4 s0 = (f32x4){0.f, 0.f, 0.f, 0.f};
        f32x4 s1 = (f32x4){0.f, 0.f, 0.f, 0.f};
        f16x8 ka[3], kb[3];
#pragma unroll
        for (int i = 0; i < 3; ++i) {
            ka[i] = *(const f16x8*)(pKt + (2 * i) * 512);
            kb[i] = *(const f16x8*)(pKt + (2 * i + 1) * 512);
        }
#pragma unroll
        for (int i = 0; i < 12; ++i) {
            const f16x8 q0 = *(const f16x8*)&sQ[((2 * i) * 4 + qr) * 128 + ql * 8];
            const f16x8 q1 = *(const f16x8*)&sQ[((2 * i + 1) * 4 + qr) * 128 + ql * 8];
            s0 = __builtin_amdgcn_mfma_f32_16x16x32_f16(q0, ka[i % 3], s0, 0, 0, 0);
            s1 = __builtin_amdgcn_mfma_f32_16x16x32_f16(q1, kb[i % 3], s1, 0, 0, 0);
            if (i + 3 < 12) {
                ka[i % 3] = *(const f16x8*)(pKt + (2 * (i + 3)) * 512);
                kb[i % 3] = *(const f16x8*)(pKt + (2 * (i + 3) + 1) * 512);
            }
        }
        sv = s0 + s1;
    };

    // ---- exp + causal mask + P->LDS buffer + rowsum partials ----
    auto expw = [&](int kt2, const f32x4& sv, _Float16* sPb) {
        const int n  = kt2 * 128 + 16 * w + ql;
        const int mg = m0 + qr * 4;
        const int pi = ((16 * w + ql) >> 3) * 16;
        {
            const float e = (n <= mg + 0) ? __expf(sv[0]) : 0.f;
            prs0 += e; sPb[(pi + qr * 4 + 0) * 8 + (ql & 7)] = (_Float16)e;
        }
        {
            const float e = (n <= mg + 1) ? __expf(sv[1]) : 0.f;
            prs1 += e; sPb[(pi + qr * 4 + 1) * 8 + (ql & 7)] = (_Float16)e;
        }
        {
            const float e = (n <= mg + 2) ? __expf(sv[2]) : 0.f;
            prs2 += e; sPb[(pi + qr * 4 + 2) * 8 + (ql & 7)] = (_Float16)e;
        }
        {
            const float e = (n <= mg + 3) ? __expf(sv[3]) : 0.f;
            prs3 += e; sPb[(pi + qr * 4 + 3) * 8 + (ql & 7)] = (_Float16)e;
        }
    };

    // ---- PV: ni-outer, ping-pong V-quad prefetch, hoisted P frags ----
    auto pv = [&](int kt2) {
        const _Float16* sPb = sP[kt2 & 1];
        const _Float16* pVt = pV0 + (long long)kt2 * 2048;
        f16x8 pfh[4];
#pragma unroll
        for (int k = 0; k < 4; ++k)
            pfh[k] = *(const f16x8*)&sPb[((k * 4 + qr) * 16 + ql) * 8];
        f16x8 va[4], vb[4];
#pragma unroll
        for (int k = 0; k < 4; ++k)
            va[k] = *(const f16x8*)(pVt + k * 512);
#pragma unroll
        for (int ni = 0; ni < 6; ++ni) {
            if (ni + 1 < 6) {
                if ((ni & 1) == 0) {
#pragma unroll
                    for (int k = 0; k < 4; ++k)
                        vb[k] = *(const f16x8*)(pVt + (ni + 1) * 32768 + k * 512);
                } else {
#pragma unroll
                    for (int k = 0; k < 4; ++k)
                        va[k] = *(const f16x8*)(pVt + (ni + 1) * 32768 + k * 512);
                }
            }
#pragma unroll
            for (int k = 0; k < 4; ++k)
                oacc[ni] = __builtin_amdgcn_mfma_f32_16x16x32_f16(
                    pfh[k], (ni & 1) ? vb[k] : va[k], oacc[ni], 0, 0, 0);
        }
    };

    // prologue: tile 0 -> sP[0]
    {
        f32x4 sv;
        qk_tile(0, sv);
        expw(0, sv, sP[0]);
    }
    // steady state: ONE barrier per tile; QK(kt+1) || PV(kt) overlap
    for (int kt = 0; kt < nt; ++kt) {
        __syncthreads();           // sP[kt&1] complete; sP[(kt+1)&1] free
        if (kt + 1 < nt) {
            f32x4 sv;
            qk_tile(kt + 1, sv);   // independent of PV(kt) -> interleaves
            pv(kt);
            expw(kt + 1, sv, sP[(kt + 1) & 1]);
        } else {
            pv(kt);
        }
    }

    // ---- rowsum: reduce over ql (16 lanes), then across 8 waves ----
    float r0 = prs0, r1 = prs1, r2 = prs2, r3 = prs3;
    r0 += __shfl_xor(r0, 1); r0 += __shfl_xor(r0, 2);
    r0 += __shfl_xor(r0, 4); r0 += __shfl_xor(r0, 8);
    r1 += __shfl_xor(r1, 1); r1 += __shfl_xor(r1, 2);
    r1 += __shfl_xor(r1, 4); r1 += __shfl_xor(r1, 8);
    r2 += __shfl_xor(r2, 1); r2 += __shfl_xor(r2, 2);
    r2 += __shfl_xor(r2, 4); r2 += __shfl_xor(r2, 8);
    r3 += __shfl_xor(r3, 1); r3 += __shfl_xor(r3, 2);
    r3 += __shfl_xor(r3, 4); r3 += __shfl_xor(r3, 8);
    if (ql == 0) {
        sRS[w][qr * 4 + 0] = r0; sRS[w][qr * 4 + 1] = r1;
        sRS[w][qr * 4 + 2] = r2; sRS[w][qr * 4 + 3] = r3;
    }
    __syncthreads();
    float rt[4];
#pragma unroll
    for (int rr = 0; rr < 4; ++rr) {
        float t2 = 0.f;
#pragma unroll
        for (int w2 = 0; w2 < 8; ++w2) t2 += sRS[w2][qr * 4 + rr];
        rt[rr] = 1.f / t2;
    }
    // ---- O write: rows m0+qr*4+rr, cols 96w+16ni+ql ----
#pragma unroll
    for (int ni = 0; ni < 6; ++ni) {
#pragma unroll
        for (int rr = 0; rr < 4; ++rr) {
            out[(long long)(bz * 2048 + m0 + qr * 4 + rr) * 768
                + 96 * w + 16 * ni + ql] = oacc[ni][rr] * rt[rr];
        }
    }
}

// ---------------- cvt: x -> f16 row-major, W -> f16 fragment-tiled ------
__global__ __launch_bounds__(256) void cvt_all(
    const float* __restrict__ x,  const float* __restrict__ wq,
    const float* __restrict__ wk, const float* __restrict__ wv,
    _Float16* __restrict__ xh, _Float16* __restrict__ Wht)
{
    const int ci = blockIdx.x * 256 + threadIdx.x;
    const int XC = 8192 * 768 / 8;               // 786432 x-chunks
    if (ci < XC) {
        const float4 v0 = ((const float4*)x)[ci * 2];
        const float4 v1 = ((const float4*)x)[ci * 2 + 1];
        f16x8 o = { (_Float16)v0.x, (_Float16)v0.y, (_Float16)v0.z, (_Float16)v0.w,
                    (_Float16)v1.x, (_Float16)v1.y, (_Float16)v1.z, (_Float16)v1.w };
        ((f16x8*)xh)[ci] = o;
    } else {
        // weights: one 16B tiled chunk per thread; writes coalesced.
        const int j = ci - XC;                   // < 2304*96 = 221184
        const int ql2 = j & 15, blk = j >> 4;
        const int c8 = blk % 96, grp = blk / 96;
        const int r = grp * 16 + ql2;            // 0..2303
        const int w = (r < 768) ? 0 : (r < 1536) ? 1 : 2;
        const float* src = (w == 0) ? wq : (w == 1) ? wk : wv;
        const int rr = r - w * 768;
        const float4 v0 = ((const float4*)src)[rr * 192 + c8 * 2];
        const float4 v1 = ((const float4*)src)[rr * 192 + c8 * 2 + 1];
        f16x8 o = { (_Float16)v0.x, (_Float16)v0.y, (_Float16)v0.z, (_Float16)v0.w,
                    (_Float16)v1.x, (_Float16)v1.y, (_Float16)v1.z, (_Float16)v1.w };
        ((f16x8*)Wht)[j] = o;
    }
}

extern "C" void kernel_launch(void* const* d_in, const int* in_sizes, int n_in,
                              void* d_out, int out_size, void* d_ws, size_t ws_size,
                              hipStream_t stream) {
    const float* x  = (const float*)d_in[0];
    const float* wq = (const float*)d_in[1];
    const float* wk = (const float*)d_in[2];
    const float* wv = (const float*)d_in[3];
    float* out = (float*)d_out;
    char* ws = (char*)d_ws;

    size_t off = 0;
    auto alloc = [&](size_t bytes) {
        void* p = ws + off;
        off = (off + bytes + 255) & ~(size_t)255;
        return p;
    };
    _Float16* xh  = (_Float16*)alloc(8192ll * 768 * 2);   // row-major
    _Float16* Wht = (_Float16*)alloc(2304ll * 768 * 2);   // frag-tiled
    _Float16* Qr  = (_Float16*)alloc(8192ll * 768 * 2);   // ROW-major, pre-scaled
    _Float16* Kt  = (_Float16*)alloc(8192ll * 768 * 2);   // frag-tiled
    _Float16* Vtt = (_Float16*)alloc(4ll * 768 * 2048 * 2);  // frag-tiled V^T

    const int XC = 8192 * 768 / 8, WC = 2304 * 96;
    cvt_all<<<(XC + WC) / 256, 256, 0, stream>>>(x, wq, wk, wv, xh, Wht);

    // Q/K/V projection: M=8192, N=2304, K=768 (128x128 tiles)
    gemm_qkv<<<dim3(18, 64, 1), 256, 0, stream>>>(xh, Wht, Qr, Kt, Vtt);

    // Fused causal attention: O = softmax(QK^T)V, one stripe per block
    fused_attn<<<dim3(512, 1, 1), 512, 0, stream>>>(Qr, Kt, Vtt, out);
}

// Round 14
// 201.331 us; speedup vs baseline: 1.3808x; 1.0089x over previous
//
#include <hip/hip_runtime.h>
#include <hip/hip_bf16.h>
#include <cstdint>
#include <cstddef>

// B=4, S=2048, D=768 causal attention, fp32 in/out, f16 MFMA compute.
// R14: fused v4 - MLP batching. v3 evidence: VGPR 60 (compiler sank the
// rolling prefetch -> load-use dist 0); per-tile ~10800cy vs 480cy MFMA;
// K+V (6.3MB/batch) > 4MB L2 -> fragment loads are ~600cy L3 hits paid
// ~18x serially per tile. Fix: batch loads in flat 8-reg groups (vmcnt(7)
// paid once per batch, 7 free): QK = 3 K-batches, PV = 3 V-batches
// (ni-pairs); QK(kt+1)||PV(kt) batches can overlap across the boundary.
// Register peak ~116 < 128 cap in both phases. Tripwires: VGPR must rise
// to ~110+ (else compiler re-serialized); WRITE_SIZE 24.6MB (spill).
// g0 (qkv) and cvt: frozen at verified state.
// Fragment-tiled layout: elem(r,c) at ((r>>4)*(C/8)+(c>>3))*128+(r&15)*8+(c&7)

typedef _Float16 f16x8 __attribute__((ext_vector_type(8)));
typedef float    f32x4 __attribute__((ext_vector_type(4)));

#define SOFTMAX_SCALE 0.036084391824351615f  // 1/sqrt(768)

// fragment-tiled element index; cd3 = C>>3 (chunks per 16-row group)
__device__ __forceinline__ int tix(int r, int c, int cd3) {
    return ((r >> 4) * cd3 + (c >> 3)) * 128 + ((r & 15) << 3) + (c & 7);
}

// ---------------- g0: QKV projection (verified, frozen) -----------------
__global__ __launch_bounds__(256, 2) void gemm_qkv(
    const _Float16* __restrict__ A, const _Float16* __restrict__ Bt,
    _Float16* __restrict__ OQ, _Float16* __restrict__ OK, _Float16* __restrict__ OV)
{
    const int flat = blockIdx.y * 18 + blockIdx.x;     // 0..1151, x-fast
    const int swz  = (flat & 7) * 144 + (flat >> 3);   // bijective (1152%8==0)
    const int tm = swz / 18, tn = swz % 18;
    const int m0 = tm * 128, n0 = tn * 128;
    const int tid  = threadIdx.x;
    const int lane = tid & 63, wave = tid >> 6;
    const int wm = (wave >> 1) * 64, wn = (wave & 1) * 64;
    const int qr = lane >> 4, ql = lane & 15;

    __shared__ _Float16 sA[128 * 64];

    const _Float16* Ab = A + (long long)m0 * 768;

    const _Float16* pB[4];
#pragma unroll
    for (int ni = 0; ni < 4; ++ni) {
        const int r0 = n0 + wn + ni * 16;
        pB[ni] = Bt + ((r0 >> 4) * 96 + qr) * 128 + ql * 8;
    }

    const int kIters = 768 / 64;

    f32x4 acc[4][4];
#pragma unroll
    for (int i = 0; i < 4; ++i)
#pragma unroll
        for (int j = 0; j < 4; ++j) acc[i][j] = (f32x4){0.f, 0.f, 0.f, 0.f};

    int sra[4], sgc[4];
#pragma unroll
    for (int t = 0; t < 4; ++t) {
        const int c = t * 256 + tid, r = c >> 3;
        sra[t] = r; sgc[t] = (c & 7) ^ (r & 7);
    }

    f16x8 pa[4];
    auto loadA = [&](int kt) {
        const int kk = kt * 64;
#pragma unroll
        for (int t = 0; t < 4; ++t)
            pa[t] = *(const f16x8*)(Ab + sra[t] * 768 + kk + sgc[t] * 8);
    };

    loadA(0);
    for (int kt = 0; kt < kIters; ++kt) {
#pragma unroll
        for (int t = 0; t < 4; ++t) ((f16x8*)sA)[t * 256 + tid] = pa[t];
        __syncthreads();

        f16x8 bF[2][4];
#pragma unroll
        for (int ks = 0; ks < 2; ++ks)
#pragma unroll
            for (int ni = 0; ni < 4; ++ni)
                bF[ks][ni] = *(const f16x8*)(pB[ni] + kt * 1024 + ks * 512);

        if (kt + 1 < kIters) loadA(kt + 1);

#pragma unroll
        for (int ks = 0; ks < 2; ++ks) {
            f16x8 aF[4];
#pragma unroll
            for (int mi = 0; mi < 4; ++mi) {
                const int r = wm + mi * 16 + ql;
                const int sc = (ks * 4 + qr) ^ (r & 7);
                aF[mi] = *(const f16x8*)&sA[r * 64 + sc * 8];
            }
#pragma unroll
            for (int mi = 0; mi < 4; ++mi)
#pragma unroll
                for (int ni = 0; ni < 4; ++ni)
                    acc[mi][ni] = __builtin_amdgcn_mfma_f32_16x16x32_f16(
                        aF[mi], bF[ks][ni], acc[mi][ni], 0, 0, 0);
        }
        __syncthreads();
    }

#pragma unroll
    for (int mi = 0; mi < 4; ++mi) {
#pragma unroll
        for (int ni = 0; ni < 4; ++ni) {
            const f32x4 v = acc[mi][ni];
            const int mbase = m0 + wm + mi * 16 + qr * 4;
            const int n     = n0 + wn + ni * 16 + ql;
#pragma unroll
            for (int r = 0; r < 4; ++r) {
                const int m = mbase + r;
                const float val = v[r];
                if (n < 768) {
                    // Q: ROW-MAJOR, pre-scaled (A-side of fused LDS path)
                    OQ[(long long)m * 768 + n] = (_Float16)(val * SOFTMAX_SCALE);
                } else if (n < 1536) {
                    OK[tix(m, n - 768, 96)] = (_Float16)val;
                } else {
                    const int b = m >> 11, s = m & 2047;
                    OV[tix(b * 768 + (n - 1536), s, 256)] = (_Float16)val;
                }
            }
        }
    }
}

// ---------------- fused v4: O = softmax(QK^T, causal) V -----------------
__global__ __launch_bounds__(512, 4) void fused_attn(
    const _Float16* __restrict__ Qr, const _Float16* __restrict__ Kt,
    const _Float16* __restrict__ Vtt, float* __restrict__ out)
{
    __shared__ _Float16 sQ[16 * 768];    // fragment-tiled: idx8 = c8*16 + r
    __shared__ _Float16 sP[2][16 * 128]; // double-buffered P relay
    __shared__ float    sRS[8][16];

    // Block -> (batch, stripe): XCD x gets 32 complete complementary pairs
    // (544 tile-units each, balanced); pair members 32-apart in dispatch.
    const int b   = blockIdx.x;                 // 0..511
    const int x   = b & 7, j = b >> 3;          // XCD, 0..63
    const int m_  = (j >> 5) & 1;               // pair member
    const int pg  = x * 32 + (j & 31);          // pair 0..255
    const int bz  = pg >> 6;                    // batch 0..3
    const int pr  = pg & 63;                    // pair in batch
    const int s   = m_ ? pr : (127 - pr);       // stripe 0..127 (heavy first)
    const int m0  = s * 16;

    const int tid = threadIdx.x;
    const int lane = tid & 63, w = tid >> 6;    // wave 0..7
    const int qr = lane >> 4, ql = lane & 15;

    // Kt row chunk base for this wave (kv tile 0): row = bz*2048 + 16w
    const _Float16* pK0 = Kt + (((bz * 2048 + 16 * w) >> 4) * 96 + qr) * 128 + ql * 8;
    // Vtt row chunk base: row = bz*768 + 96w (+16*ni later)
    const _Float16* pV0 = Vtt + (((bz * 768 + 96 * w) >> 4) * 256 + qr) * 128 + ql * 8;

    // stage Q (16x768) fragment-tiled into LDS; each thread 3 chunks
#pragma unroll
    for (int t = 0; t < 3; ++t) {
        const int jj = t * 512 + tid;           // 0..1535
        const int r = jj & 15, c8 = jj >> 4;    // c8 0..95
        ((f16x8*)sQ)[c8 * 16 + r] =
            *(const f16x8*)(Qr + (long long)(bz * 2048 + m0 + r) * 768 + c8 * 8);
    }
    __syncthreads();

    const int nt = (s >> 3) + 1;                // causal KV tiles of 128

    f32x4 oacc[6];
#pragma unroll
    for (int i = 0; i < 6; ++i) oacc[i] = (f32x4){0.f, 0.f, 0.f, 0.f};
    float prs0 = 0.f, prs1 = 0.f, prs2 = 0.f, prs3 = 0.f;

    // ---- QK tile: 3 batches of 8 in-flight K loads (MLP), 2 acc chains ----
    auto qk_tile = [&](int kt2, f32x4& sv) {
        const _Float16* pKt = pK0 + (long long)kt2 * 98304;
        f32x4 s0 = (f32x4){0.f, 0.f, 0.f, 0.f};
        f32x4 s1 = (f32x4){0.f, 0.f, 0.f, 0.f};
#pragma unroll
        for (int b3 = 0; b3 < 3; ++b3) {
            f16x8 kr[8];
#pragma unroll
            for (int t = 0; t < 8; ++t)
                kr[t] = *(const f16x8*)(pKt + (b3 * 8 + t) * 512);
#pragma unroll
            for (int t = 0; t < 8; ++t) {
                const f16x8 q =
                    *(const f16x8*)&sQ[((b3 * 8 + t) * 4 + qr) * 128 + ql * 8];
                if (t & 1)
                    s1 = __builtin_amdgcn_mfma_f32_16x16x32_f16(q, kr[t], s1, 0, 0, 0);
                else
                    s0 = __builtin_amdgcn_mfma_f32_16x16x32_f16(q, kr[t], s0, 0, 0, 0);
            }
        }
        sv = s0 + s1;
    };

    // ---- exp + causal mask + P->LDS buffer + rowsum partials ----
    auto expw = [&](int kt2, const f32x4& sv, _Float16* sPb) {
        const int n  = kt2 * 128 + 16 * w + ql;
        const int mg = m0 + qr * 4;
        const int pi = ((16 * w + ql) >> 3) * 16;
        {
            const float e = (n <= mg + 0) ? __expf(sv[0]) : 0.f;
            prs0 += e; sPb[(pi + qr * 4 + 0) * 8 + (ql & 7)] = (_Float16)e;
        }
        {
            const float e = (n <= mg + 1) ? __expf(sv[1]) : 0.f;
            prs1 += e; sPb[(pi + qr * 4 + 1) * 8 + (ql & 7)] = (_Float16)e;
        }
        {
            const float e = (n <= mg + 2) ? __expf(sv[2]) : 0.f;
            prs2 += e; sPb[(pi + qr * 4 + 2) * 8 + (ql & 7)] = (_Float16)e;
        }
        {
            const float e = (n <= mg + 3) ? __expf(sv[3]) : 0.f;
            prs3 += e; sPb[(pi + qr * 4 + 3) * 8 + (ql & 7)] = (_Float16)e;
        }
    };

    // ---- PV: 3 batches of 8 in-flight V loads (ni-pairs), hoisted P ----
    auto pv = [&](int kt2) {
        const _Float16* sPb = sP[kt2 & 1];
        const _Float16* pVt = pV0 + (long long)kt2 * 2048;
        f16x8 pfh[4];
#pragma unroll
        for (int k = 0; k < 4; ++k)
            pfh[k] = *(const f16x8*)&sPb[((k * 4 + qr) * 16 + ql) * 8];
#pragma unroll
        for (int g = 0; g < 3; ++g) {
            f16x8 vr[8];
#pragma unroll
            for (int k = 0; k < 4; ++k) {
                vr[k]     = *(const f16x8*)(pVt + (2 * g) * 32768 + k * 512);
                vr[4 + k] = *(const f16x8*)(pVt + (2 * g + 1) * 32768 + k * 512);
            }
#pragma unroll
            for (int k = 0; k < 4; ++k)
                oacc[2 * g] = __builtin_amdgcn_mfma_f32_16x16x32_f16(
                    pfh[k], vr[k], oacc[2 * g], 0, 0, 0);
#pragma unroll
            for (int k = 0; k < 4; ++k)
                oacc[2 * g + 1] = __builtin_amdgcn_mfma_f32_16x16x32_f16(
                    pfh[k], vr[4 + k], oacc[2 * g + 1], 0, 0, 0);
        }
    };

    // prologue: tile 0 -> sP[0]
    {
        f32x4 sv;
        qk_tile(0, sv);
        expw(0, sv, sP[0]);
    }
    // steady state: ONE barrier per tile; QK(kt+1) || PV(kt) overlap
    for (int kt = 0; kt < nt; ++kt) {
        __syncthreads();           // sP[kt&1] complete; sP[(kt+1)&1] free
        if (kt + 1 < nt) {
            f32x4 sv;
            qk_tile(kt + 1, sv);   // independent of PV(kt) -> interleaves
            pv(kt);
            expw(kt + 1, sv, sP[(kt + 1) & 1]);
        } else {
            pv(kt);
        }
    }

    // ---- rowsum: reduce over ql (16 lanes), then across 8 waves ----
    float r0 = prs0, r1 = prs1, r2 = prs2, r3 = prs3;
    r0 += __shfl_xor(r0, 1); r0 += __shfl_xor(r0, 2);
    r0 += __shfl_xor(r0, 4); r0 += __shfl_xor(r0, 8);
    r1 += __shfl_xor(r1, 1); r1 += __shfl_xor(r1, 2);
    r1 += __shfl_xor(r1, 4); r1 += __shfl_xor(r1, 8);
    r2 += __shfl_xor(r2, 1); r2 += __shfl_xor(r2, 2);
    r2 += __shfl_xor(r2, 4); r2 += __shfl_xor(r2, 8);
    r3 += __shfl_xor(r3, 1); r3 += __shfl_xor(r3, 2);
    r3 += __shfl_xor(r3, 4); r3 += __shfl_xor(r3, 8);
    if (ql == 0) {
        sRS[w][qr * 4 + 0] = r0; sRS[w][qr * 4 + 1] = r1;
        sRS[w][qr * 4 + 2] = r2; sRS[w][qr * 4 + 3] = r3;
    }
    __syncthreads();
    float rt[4];
#pragma unroll
    for (int rr = 0; rr < 4; ++rr) {
        float t2 = 0.f;
#pragma unroll
        for (int w2 = 0; w2 < 8; ++w2) t2 += sRS[w2][qr * 4 + rr];
        rt[rr] = 1.f / t2;
    }
    // ---- O write: rows m0+qr*4+rr, cols 96w+16ni+ql ----
#pragma unroll
    for (int ni = 0; ni < 6; ++ni) {
#pragma unroll
        for (int rr = 0; rr < 4; ++rr) {
            out[(long long)(bz * 2048 + m0 + qr * 4 + rr) * 768
                + 96 * w + 16 * ni + ql] = oacc[ni][rr] * rt[rr];
        }
    }
}

// ---------------- cvt: x -> f16 row-major, W -> f16 fragment-tiled ------
__global__ __launch_bounds__(256) void cvt_all(
    const float* __restrict__ x,  const float* __restrict__ wq,
    const float* __restrict__ wk, const float* __restrict__ wv,
    _Float16* __restrict__ xh, _Float16* __restrict__ Wht)
{
    const int ci = blockIdx.x * 256 + threadIdx.x;
    const int XC = 8192 * 768 / 8;               // 786432 x-chunks
    if (ci < XC) {
        const float4 v0 = ((const float4*)x)[ci * 2];
        const float4 v1 = ((const float4*)x)[ci * 2 + 1];
        f16x8 o = { (_Float16)v0.x, (_Float16)v0.y, (_Float16)v0.z, (_Float16)v0.w,
                    (_Float16)v1.x, (_Float16)v1.y, (_Float16)v1.z, (_Float16)v1.w };
        ((f16x8*)xh)[ci] = o;
    } else {
        // weights: one 16B tiled chunk per thread; writes coalesced.
        const int j = ci - XC;                   // < 2304*96 = 221184
        const int ql2 = j & 15, blk = j >> 4;
        const int c8 = blk % 96, grp = blk / 96;
        const int r = grp * 16 + ql2;            // 0..2303
        const int w = (r < 768) ? 0 : (r < 1536) ? 1 : 2;
        const float* src = (w == 0) ? wq : (w == 1) ? wk : wv;
        const int rr = r - w * 768;
        const float4 v0 = ((const float4*)src)[rr * 192 + c8 * 2];
        const float4 v1 = ((const float4*)src)[rr * 192 + c8 * 2 + 1];
        f16x8 o = { (_Float16)v0.x, (_Float16)v0.y, (_Float16)v0.z, (_Float16)v0.w,
                    (_Float16)v1.x, (_Float16)v1.y, (_Float16)v1.z, (_Float16)v1.w };
        ((f16x8*)Wht)[j] = o;
    }
}

extern "C" void kernel_launch(void* const* d_in, const int* in_sizes, int n_in,
                              void* d_out, int out_size, void* d_ws, size_t ws_size,
                              hipStream_t stream) {
    const float* x  = (const float*)d_in[0];
    const float* wq = (const float*)d_in[1];
    const float* wk = (const float*)d_in[2];
    const float* wv = (const float*)d_in[3];
    float* out = (float*)d_out;
    char* ws = (char*)d_ws;

    size_t off = 0;
    auto alloc = [&](size_t bytes) {
        void* p = ws + off;
        off = (off + bytes + 255) & ~(size_t)255;
        return p;
    };
    _Float16* xh  = (_Float16*)alloc(8192ll * 768 * 2);   // row-major
    _Float16* Wht = (_Float16*)alloc(2304ll * 768 * 2);   // frag-tiled
    _Float16* Qr  = (_Float16*)alloc(8192ll * 768 * 2);   // ROW-major, pre-scaled
    _Float16* Kt  = (_Float16*)alloc(8192ll * 768 * 2);   // frag-tiled
    _Float16* Vtt = (_Float16*)alloc(4ll * 768 * 2048 * 2);  // frag-tiled V^T

    const int XC = 8192 * 768 / 8, WC = 2304 * 96;
    cvt_all<<<(XC + WC) / 256, 256, 0, stream>>>(x, wq, wk, wv, xh, Wht);

    // Q/K/V projection: M=8192, N=2304, K=768 (128x128 tiles)
    gemm_qkv<<<dim3(18, 64, 1), 256, 0, stream>>>(xh, Wht, Qr, Kt, Vtt);

    // Fused causal attention: O = softmax(QK^T)V, one stripe per block
    fused_attn<<<dim3(512, 1, 1), 512, 0, stream>>>(Qr, Kt, Vtt, out);
}